// Round 8
// baseline (1176.713 us; speedup 1.0000x reference)
//
#include <hip/hip_runtime.h>
#include <hip/hip_bf16.h>
#include <math.h>

#define D_MODEL 1024
#define D_INNER 2048
#define NSTATE  16
#define BATCH   4
#define SEQ     4096
#define MTOT    (BATCH*SEQ)      // 16384
#define SDT     2176             // dtBC row stride: 2048 dt | 16 B | 16 C | 96 pad
#define NCATP   2304             // [Wdt;WB;WC;zeros] rows padded to 9*256
#define NBIG    6272             // fused GEMM N: 2048 xs | 2048 z | 2048 dt | 32 BC | 96 pad
#define NCHUNK  16
#define CLEN    (SEQ/NCHUNK)     // 256
#define N1      (2*D_INNER)      // 4096

typedef __attribute__((ext_vector_type(8))) __bf16 bf16x8;
typedef __attribute__((ext_vector_type(4))) float f32x4;

__device__ __forceinline__ float b2f(unsigned short u){
  return __uint_as_float(((unsigned int)u) << 16);
}
__device__ __forceinline__ unsigned short f2b(float f){
  unsigned int u = __float_as_uint(f);
  u = (u + 0x7FFFu + ((u >> 16) & 1u)) >> 16;   // RNE
  return (unsigned short)u;
}
__device__ __forceinline__ float softplus_f(float x){
  float r = log1pf(__expf(-fabsf(x)));
  return x > 0.f ? x + r : r;
}

// async 16B global -> LDS (DMA; LDS dst = wave-uniform base + lane*16)
__device__ __forceinline__ void async16(unsigned short* lds, const unsigned short* g){
  __builtin_amdgcn_global_load_lds(
      (const __attribute__((address_space(1))) unsigned int*)g,
      (__attribute__((address_space(3))) unsigned int*)lds, 16, 0, 0);
}

// ---- f32 -> bf16 convert (4 elems/thread) ----
__global__ void cvt_f2b_kernel(const float* __restrict__ src,
                               unsigned short* __restrict__ dst){
  int i = (blockIdx.x * 256 + threadIdx.x) * 4;
  float4 v = *(const float4*)(src + i);
  *(ushort2*)(dst + i)     = (ushort2){f2b(v.x), f2b(v.y)};
  *(ushort2*)(dst + i + 2) = (ushort2){f2b(v.z), f2b(v.w)};
}

// ---- build Acomp(bf16) = [W_dt(2048); W_B(16); W_C(16); zeros(224)] : 2304x2048 ----
__global__ void concat_w_kernel(const float* __restrict__ Wdt,
                                const float* __restrict__ WB,
                                const float* __restrict__ WC,
                                unsigned short* __restrict__ Wcat){
  int idx = blockIdx.x * 256 + threadIdx.x;   // 4-elem granularity
  int row = idx >> 9;                         // 2048 cols = 512 quads/row
  int q   = idx & 511;
  float4 v;
  if      (row < 2048) v = *(const float4*)(Wdt + ((size_t)row * 2048 + q * 4));
  else if (row < 2064) v = *(const float4*)(WB  + ((size_t)(row - 2048) * 2048 + q * 4));
  else if (row < 2080) v = *(const float4*)(WC  + ((size_t)(row - 2064) * 2048 + q * 4));
  else                 v = make_float4(0.f, 0.f, 0.f, 0.f);
  unsigned short* p = Wcat + (size_t)idx * 4;
  *(ushort2*)(p)     = (ushort2){f2b(v.x), f2b(v.y)};
  *(ushort2*)(p + 2) = (ushort2){f2b(v.z), f2b(v.w)};
}

// ---- WxT[k,e] = Win[e,k] (bf16), k<1024, e<2048 (x_ssm half of W_in) ----
__global__ __launch_bounds__(256) void transpose_cvt_kernel(
    const float* __restrict__ Win, unsigned short* __restrict__ WxT){
  __shared__ float t[64][65];
  const int e0 = blockIdx.x * 64;       // source row block (e)
  const int k0 = blockIdx.y * 64;       // source col block (k)
  const int r  = threadIdx.x >> 2;      // 0..63
  const int q  = threadIdx.x & 3;       // 0..3
  #pragma unroll
  for (int jj = 0; jj < 4; jj++){
    float4 v = *(const float4*)&Win[(size_t)(e0 + r) * 1024 + k0 + q*16 + jj*4];
    t[r][q*16 + jj*4 + 0] = v.x; t[r][q*16 + jj*4 + 1] = v.y;
    t[r][q*16 + jj*4 + 2] = v.z; t[r][q*16 + jj*4 + 3] = v.w;
  }
  __syncthreads();
  // out row k0+r, cols e0 + q*16 .. +16
  #pragma unroll
  for (int jj = 0; jj < 2; jj++){
    ushort4 o;
    o.x = f2b(t[q*16 + jj*8 + 0][r]); o.y = f2b(t[q*16 + jj*8 + 1][r]);
    o.z = f2b(t[q*16 + jj*8 + 2][r]); o.w = f2b(t[q*16 + jj*8 + 3][r]);
    *(ushort4*)&WxT[(size_t)(k0 + r) * 2048 + e0 + q*16 + jj*8] = o;
    o.x = f2b(t[q*16 + jj*8 + 4][r]); o.y = f2b(t[q*16 + jj*8 + 5][r]);
    o.z = f2b(t[q*16 + jj*8 + 6][r]); o.w = f2b(t[q*16 + jj*8 + 7][r]);
    *(ushort4*)&WxT[(size_t)(k0 + r) * 2048 + e0 + q*16 + jj*8 + 4] = o;
  }
}

// ---- zero-fill (1 ushort/thread x 1 elem granularity via grid sizing) ----
__global__ void zfill_kernel(unsigned short* __restrict__ p){
  p[blockIdx.x * 256 + threadIdx.x] = 0;
}

// ============================================================================
// GEMM: C[M,N] = A[M,K] @ W[N,K]^T, bf16 MFMA, fp32 acc, fused epilogues.
// 256x128 tile, 512 thr = 8 waves mapped 4m x 2n -> per-wave output 64x64.
// r7-verified schedule, unchanged: 4-phase iter (2 K-tiles BK=64), LDS 96 KiB
// (A 2x32K, B 2x16K), counted vmcnt(4) only at P2/P4, chunk-XOR LDS swizzle
// (pre-swizzled global source, linear DMA dst), no sched_barrier fences.
//  P1 rd buf0.A(all)+B(h0)  st buf1.B  <-t0+1 (2 ld)
//  P2 rd buf0.B(h1)         st buf0.A  <-t0+2 (4 ld); vmcnt(4)
//  P3 rd buf1.A(all)+B(h0)  st buf0.B  <-t0+2 (2 ld)
//  P4 rd buf1.B(h1)         st buf1.A  <-t0+3 (4 ld); vmcnt(4)
// Prologue: A0,B0,A1 (10 ld), vmcnt(4). Last iter: no stages, vmcnt(0)@P2.
//
// MODE 0 (fused big GEMM, N=6272 over W = Wcomb):
//   col<2048  -> o0 = xs                                   [bf16]
//   col<4096  -> o1 = z (col-2048)                         [bf16]
//   col<6144  -> o2 = dtBC dt: softplus(v+bias[col-4096]), stride SDT
//   col<6176  -> o2 = dtBC B/C at +2048+(col-6144)
//   else drop (pad)
// MODE 2: v * sigmoid(bias[0]); store f32 into of (row stride D_MODEL)
// MODE 3: plain bf16 store o0[row*1024+col], guard row<2080 (weight compose)
// ============================================================================
template<int MODE, int K, int GX, int GY>
__global__ __launch_bounds__(512, 1) void gemm_bt(
    const unsigned short* __restrict__ A,
    const unsigned short* __restrict__ W,
    unsigned short* __restrict__ o0,
    unsigned short* __restrict__ o1,
    unsigned short* __restrict__ o2,
    float* __restrict__ of,
    const float* __restrict__ bias)
{
  const int tid  = threadIdx.x;
  const int lane = tid & 63;
  const int w    = tid >> 6;            // 0..7
  const int wm   = w >> 1;              // 0..3 : 64-row quarter of tile
  const int wn   = w & 1;               // 0..1 : 64-col half of tile
  const int m16  = lane & 15, q = lane >> 4;

  // XCD-aware bijective swizzle; NWG % 8 == 0 for all launches
  constexpr int NWG = GX * GY;
  int flat = blockIdx.y * GX + blockIdx.x;
  flat = (flat & 7) * (NWG >> 3) + (flat >> 3);
  const int bm = flat / GX;             // const divisor -> magic mul
  const int bn = flat - bm * GX;

  __shared__ unsigned short sA[2][16384];   // 2 x (256 rows x 64 k) = 2 x 32 KB
  __shared__ unsigned short sB[2][8192];    // 2 x (128 rows x 64 k) = 2 x 16 KB

  f32x4 acc[4][4];
  #pragma unroll
  for (int i = 0; i < 4; i++)
    #pragma unroll
    for (int j = 0; j < 4; j++) acc[i][j] = (f32x4){0.f, 0.f, 0.f, 0.f};

  // stager: thread -> (row = tid>>3 within 64-row unit, slot = tid&7);
  // fetched global k-chunk = slot ^ (row&7) (pre-swizzled source)
  const int ch = (tid & 7) ^ ((tid >> 3) & 7);
  const unsigned short* Ag = A + (size_t)(bm * 256 + (tid >> 3)) * K + ch * 8;
  const unsigned short* Wg = W + (size_t)(bn * 128 + (tid >> 3)) * K + ch * 8;

#define STAGE_A(buf, h, t) do { \
    async16(&sA[buf][(h)*8192 + w*512],        Ag + (size_t)((h)*128    )*K + (t)*64); \
    async16(&sA[buf][(h)*8192 + 4096 + w*512], Ag + (size_t)((h)*128 + 64)*K + (t)*64); \
  } while(0)
#define STAGE_B(buf, t) do { \
    async16(&sB[buf][w*512],        Wg + (size_t)(t)*64); \
    async16(&sB[buf][4096 + w*512], Wg + (size_t)64*K + (t)*64); \
  } while(0)

  // fragment reads: row r, k-chunk kc=(kk*4+q) lives at slot kc^(r&7); r&7==m16&7
#define LDA(dst, buf) do { \
    _Pragma("unroll") for (int mt = 0; mt < 4; mt++) \
    _Pragma("unroll") for (int kk = 0; kk < 2; kk++) { \
      const int row_ = wm*64 + mt*16 + m16; \
      dst[mt][kk] = *(const bf16x8*)&sA[buf][row_*64 + (((kk*4 + q) ^ (m16 & 7)) << 3)]; \
    } } while(0)
#define LDB(dst, buf, nh) do { \
    _Pragma("unroll") for (int nt = 0; nt < 2; nt++) \
    _Pragma("unroll") for (int kk = 0; kk < 2; kk++) { \
      const int row_ = wn*64 + (nh)*32 + nt*16 + m16; \
      dst[nt][kk] = *(const bf16x8*)&sB[buf][row_*64 + (((kk*4 + q) ^ (m16 & 7)) << 3)]; \
    } } while(0)

#define MMAQ(Aa, Bb, NH) do { \
    __builtin_amdgcn_s_setprio(1); \
    _Pragma("unroll") for (int kk = 0; kk < 2; kk++) \
    _Pragma("unroll") for (int mt = 0; mt < 4; mt++) \
    _Pragma("unroll") for (int nt = 0; nt < 2; nt++) \
      acc[mt][(NH)*2 + nt] = __builtin_amdgcn_mfma_f32_16x16x32_bf16( \
          Aa[mt][kk], Bb[nt][kk], acc[mt][(NH)*2 + nt], 0, 0, 0); \
    __builtin_amdgcn_s_setprio(0); \
  } while(0)

#define BAR()  asm volatile("s_barrier" ::: "memory")
#define LGK0() asm volatile("s_waitcnt lgkmcnt(0)" ::: "memory")

  // ---- prologue: buf0 <- tile0 (A 4ld + B 2ld), buf1.A <- tile1 (4ld)
  STAGE_A(0, 0, 0); STAGE_A(0, 1, 0); STAGE_B(0, 0);
  STAGE_A(1, 0, 1); STAGE_A(1, 1, 1);
  asm volatile("s_waitcnt vmcnt(4)" ::: "memory");   // buf0 complete; buf1.A in flight
  BAR();

  auto run_iter = [&](int t0, bool last) {
    bf16x8 a[4][2], b[2][2];
    // ---- P1: buf0, B-half0 (A full) ----
    LDA(a, 0); LDB(b, 0, 0);
    STAGE_B(1, t0 + 1);
    BAR(); LGK0();
    MMAQ(a, b, 0);
    BAR();
    // ---- P2: buf0, B-half1 (a held) ----
    LDB(b, 0, 1);
    if (!last) { STAGE_A(0, 0, t0 + 2); STAGE_A(0, 1, t0 + 2); }
    BAR(); LGK0();
    MMAQ(a, b, 1);
    if (last) asm volatile("s_waitcnt vmcnt(0)" ::: "memory");
    else      asm volatile("s_waitcnt vmcnt(4)" ::: "memory");
    BAR();
    // ---- P3: buf1, B-half0 (A full) ----
    LDA(a, 1); LDB(b, 1, 0);
    if (!last) STAGE_B(0, t0 + 2);
    BAR(); LGK0();
    MMAQ(a, b, 0);
    BAR();
    // ---- P4: buf1, B-half1 (a held) ----
    LDB(b, 1, 1);
    if (!last) { STAGE_A(1, 0, t0 + 3); STAGE_A(1, 1, t0 + 3); }
    BAR(); LGK0();
    MMAQ(a, b, 1);
    if (!last) asm volatile("s_waitcnt vmcnt(4)" ::: "memory");
    BAR();
  };

  constexpr int NIT = K >> 7;          // K / 128 (two 64-K tiles per iter)
  #pragma unroll 1
  for (int j = 0; j < NIT - 1; j++) run_iter(2 * j, false);
  run_iter(2 * (NIT - 1), true);

  float gscale = 1.f;
  if (MODE == 2) gscale = 1.f / (1.f + __expf(-bias[0]));

  // C/D layout: col = lane&15, row = (lane>>4)*4 + reg
  const int r0 = bm * 256 + wm * 64 + (q << 2);
  const int c0 = bn * 128 + wn * 64 + m16;
  #pragma unroll
  for (int mt = 0; mt < 4; mt++) {
    #pragma unroll
    for (int nt = 0; nt < 4; nt++) {
      const int col = c0 + nt * 16;
      #pragma unroll
      for (int i = 0; i < 4; i++) {
        const int row = r0 + mt * 16 + i;
        float v = acc[mt][nt][i];
        if (MODE == 0) {
          if      (col < 2048) o0[(size_t)row * D_INNER + col] = f2b(v);
          else if (col < 4096) o1[(size_t)row * D_INNER + (col - 2048)] = f2b(v);
          else if (col < 6144) o2[(size_t)row * SDT + (col - 4096)] =
                                   f2b(softplus_f(v + bias[col - 4096]));
          else if (col < 6176) o2[(size_t)row * SDT + 2048 + (col - 6144)] = f2b(v);
        } else if (MODE == 2) {
          of[(size_t)row * D_MODEL + col] = v * gscale;
        } else {  // MODE 3: weight compose, plain bf16, row stride 1024
          if (row < 2080) o0[(size_t)row * D_MODEL + col] = f2b(v);
        }
      }
    }
  }
#undef STAGE_A
#undef STAGE_B
#undef LDA
#undef LDB
#undef MMAQ
#undef BAR
#undef LGK0
}

// ---- scan pass A: per chunk, per (b,d,n): P = prod A_bar, S = chunk inlet ----
__global__ __launch_bounds__(256) void scan_passA(
    const unsigned short* __restrict__ dtBC,
    const unsigned short* __restrict__ xs,
    const float* __restrict__ Alog,
    float* __restrict__ Pb, float* __restrict__ Sb)
{
  const int d = blockIdx.x * 256 + threadIdx.x;
  const int b = blockIdx.y;
  const int c = blockIdx.z;

  float a[NSTATE];
  #pragma unroll
  for (int n = 0; n < NSTATE; n++) a[n] = -__expf(Alog[d * NSTATE + n]);

  float P[NSTATE], S[NSTATE];
  #pragma unroll
  for (int n = 0; n < NSTATE; n++) { P[n] = 1.f; S[n] = 0.f; }

  __shared__ float sB[16][16];
  const size_t bL = (size_t)b * SEQ;
  const int t0c = c * CLEN;
  const int lt = threadIdx.x >> 4, ln = threadIdx.x & 15;

  for (int t0 = t0c; t0 < t0c + CLEN; t0 += 16) {
    __syncthreads();
    sB[lt][ln] = b2f(dtBC[(bL + t0 + lt) * SDT + 2048 + ln]);
    __syncthreads();
    for (int tt = 0; tt < 16; tt++) {
      const size_t rw = bL + t0 + tt;
      const float dt = b2f(dtBC[rw * SDT + d]);
      const float x  = b2f(xs[rw * D_INNER + d]);
      const float dtx = dt * x;
      #pragma unroll
      for (int n = 0; n < NSTATE; n++) {
        const float ab = __expf(dt * a[n]);   // dt>=0, a<0 => clamp(.,20) dead
        P[n] *= ab;
        S[n] = ab * S[n] + dtx * sB[tt][n];
      }
    }
  }
  const size_t base = (((size_t)c * BATCH + b) * D_INNER + d) * NSTATE;
  #pragma unroll
  for (int n = 0; n < NSTATE; n += 4) {
    *(f32x4*)&Pb[base + n] = (f32x4){P[n], P[n+1], P[n+2], P[n+3]};
    *(f32x4*)&Sb[base + n] = (f32x4){S[n], S[n+1], S[n+2], S[n+3]};
  }
}

// ---- scan pass B: sequential combine across chunks; Pb[c] <- h entering c ----
__global__ __launch_bounds__(256) void scan_passB(float* __restrict__ Pb,
                                                  const float* __restrict__ Sb)
{
  const size_t j = (size_t)blockIdx.x * 256 + threadIdx.x;  // (b,d,n) flat
  const size_t stride = (size_t)BATCH * D_INNER * NSTATE;
  float h = 0.f;
  for (int c = 0; c < NCHUNK; c++) {
    const size_t idx = (size_t)c * stride + j;
    const float p = Pb[idx];
    const float s = Sb[idx];
    Pb[idx] = h;
    h = p * h + s;
  }
}

// ---- scan pass C: re-scan chunk with true h0; y=(scan + x*D)*silu(z) ----
// NOTE: yb may alias zb (each thread reads z[rw,d] before writing y[rw,d]).
__global__ __launch_bounds__(256) void scan_passC(
    const unsigned short* __restrict__ dtBC,
    const unsigned short* __restrict__ xs,
    const unsigned short* __restrict__ zb,
    const float* __restrict__ Alog,
    const float* __restrict__ Dv,
    const float* __restrict__ Hb,
    unsigned short* __restrict__ yb)
{
  const int d = blockIdx.x * 256 + threadIdx.x;
  const int b = blockIdx.y;
  const int c = blockIdx.z;

  float a[NSTATE];
  #pragma unroll
  for (int n = 0; n < NSTATE; n++) a[n] = -__expf(Alog[d * NSTATE + n]);

  float h[NSTATE];
  const size_t base = (((size_t)c * BATCH + b) * D_INNER + d) * NSTATE;
  #pragma unroll
  for (int n = 0; n < NSTATE; n += 4) {
    f32x4 v = *(const f32x4*)&Hb[base + n];
    h[n] = v.x; h[n+1] = v.y; h[n+2] = v.z; h[n+3] = v.w;
  }
  const float Dd = Dv[d];

  __shared__ float sB[16][16];
  __shared__ float sC[16][16];
  const size_t bL = (size_t)b * SEQ;
  const int t0c = c * CLEN;
  const int lt = threadIdx.x >> 4, ln = threadIdx.x & 15;

  for (int t0 = t0c; t0 < t0c + CLEN; t0 += 16) {
    __syncthreads();
    {
      const size_t rwb = (bL + t0 + lt) * SDT + 2048;
      sB[lt][ln] = b2f(dtBC[rwb + ln]);
      sC[lt][ln] = b2f(dtBC[rwb + 16 + ln]);
    }
    __syncthreads();
    for (int tt = 0; tt < 16; tt++) {
      const size_t rw = bL + t0 + tt;
      const float dt = b2f(dtBC[rw * SDT + d]);
      const float x  = b2f(xs[rw * D_INNER + d]);
      const float z  = b2f(zb[rw * D_INNER + d]);
      const float dtx = dt * x;
      float y = 0.f;
      #pragma unroll
      for (int n = 0; n < NSTATE; n++) {
        const float ab = __expf(dt * a[n]);
        h[n] = ab * h[n] + dtx * sB[tt][n];
        y += h[n] * sC[tt][n];
      }
      y = (y + x * Dd) * (z / (1.f + __expf(-z)));   // +x*D, *silu(z)
      yb[rw * D_INNER + d] = f2b(y);
    }
  }
}

extern "C" void kernel_launch(void* const* d_in, const int* in_sizes, int n_in,
                              void* d_out, int out_size, void* d_ws, size_t ws_size,
                              hipStream_t stream)
{
  const float* x    = (const float*)d_in[0];   // (4,4096,1024)
  const float* Win  = (const float*)d_in[1];   // (4096,1024)
  const float* Alog = (const float*)d_in[2];   // (2048,16)
  const float* WB   = (const float*)d_in[3];   // (16,2048)
  const float* WC   = (const float*)d_in[4];   // (16,2048)
  const float* Wdt  = (const float*)d_in[5];   // (2048,2048)
  const float* bdt  = (const float*)d_in[6];   // (2048,)
  const float* Dv   = (const float*)d_in[7];   // (2048,)
  const float* gate = (const float*)d_in[8];   // (1,)
  const float* Wout = (const float*)d_in[9];   // (1024,2048)
  float* outp = (float*)d_out;                 // (4,4096,1024) f32

  // ---- d_ws layout (208 MiB, unchanged footprint) ----
  char* ws = (char*)d_ws;
  unsigned short* xs    = (unsigned short*)(ws + 0);          // 16384x2048 bf16 (67.1 MB)
  unsigned short* zy    = (unsigned short*)(ws + 67108864);   // z, later y (aliased)
  unsigned short* dtBC  = (unsigned short*)(ws + 134217728);  // 16384x2176 bf16 (71.3 MB)
  unsigned short* WxT   = (unsigned short*)(ws + 205520896);  // 1024x2048 bf16 (4 MB, old Winb slot)
  unsigned short* Woutb = (unsigned short*)(ws + 213909504);  // 1024x2048 bf16 (4 MB)

  // ---- d_out (67.1 MB f32) doubles as scratch before final GEMM writes it ----
  // Timeline: Acomp/Wcomb/xb live pre-scan; Pb/Sb written post-main-GEMM
  // (Acomp dead by then); GEMM3 overwrites everything at the end.
  char* ob = (char*)d_out;
  float* Pb = (float*)(ob + 0);                               // 16x4x2048x16 f32 (8 MB)
  float* Sb = (float*)(ob + 8388608);                         // (8 MB)
  unsigned short* Acomp = (unsigned short*)(ob + 0);          // 2304x2048 bf16 (9.4 MB) — pre-scan only
  unsigned short* Wcomb = (unsigned short*)(ob + 16777216);   // 6272x1024 bf16 (12.8 MB)
  unsigned short* xb    = (unsigned short*)(ob + 33554432);   // 16384x1024 bf16 (33.5 MB)

  // prep: conversions + composed-weight build
  cvt_f2b_kernel<<<16384, 256, 0, stream>>>(x, xb);
  cvt_f2b_kernel<<<4096, 256, 0, stream>>>(Win, Wcomb);            // Wcomb rows 0..4095 = Win
  cvt_f2b_kernel<<<2048, 256, 0, stream>>>(Wout, Woutb);
  concat_w_kernel<<<(NCATP * D_INNER / 4) / 256, 256, 0, stream>>>(Wdt, WB, WC, Acomp);
  transpose_cvt_kernel<<<dim3(32, 16), 256, 0, stream>>>(Win, WxT);
  zfill_kernel<<<384, 256, 0, stream>>>(Wcomb + (size_t)6176 * 1024);  // pad rows 6176..6271

  // compose: Wcomb[4096+j, k] = sum_e Acomp[j,e] * Win[e,k]  (j<2080 real)
  gemm_bt<3, 2048, 8, 9><<<dim3(8, 9), 512, 0, stream>>>(
      Acomp, WxT, Wcomb + (size_t)4096 * 1024, nullptr, nullptr, nullptr, nullptr);

  // fused big GEMM: [xs | z | dt(softplus) | B C] = x @ Wcomb^T
  gemm_bt<0, D_MODEL, NBIG / 128, MTOT / 256><<<dim3(NBIG / 128, MTOT / 256), 512, 0, stream>>>(
      xb, Wcomb, xs, zy, dtBC, nullptr, bdt);

  scan_passA<<<dim3(D_INNER / 256, BATCH, NCHUNK), 256, 0, stream>>>(
      dtBC, xs, Alog, Pb, Sb);
  scan_passB<<<(BATCH * D_INNER * NSTATE) / 256, 256, 0, stream>>>(Pb, Sb);
  scan_passC<<<dim3(D_INNER / 256, BATCH, NCHUNK), 256, 0, stream>>>(
      dtBC, xs, zy, Alog, Dv, Pb, zy);
  gemm_bt<2, D_INNER, D_MODEL / 128, MTOT / 256><<<dim3(D_MODEL / 128, MTOT / 256), 512, 0, stream>>>(
      zy, Woutb, nullptr, nullptr, nullptr, outp, gate);
}

// Round 9
// 1095.957 us; speedup vs baseline: 1.0737x; 1.0737x over previous
//
#include <hip/hip_runtime.h>
#include <hip/hip_bf16.h>
#include <math.h>

#define D_MODEL 1024
#define D_INNER 2048
#define NSTATE  16
#define BATCH   4
#define SEQ     4096
#define MTOT    (BATCH*SEQ)      // 16384
#define SDT     2176             // dtBC row stride: 2048 dt | 16 B | 16 C | 96 pad
#define NCATP   2304             // [Wdt;WB;WC;zeros] rows padded to 9*256
#define NBIG    6272             // fused GEMM N: 2048 xs | 2048 z | 2048 dt | 32 BC | 96 pad
#define NCHUNK  16
#define CLEN    (SEQ/NCHUNK)     // 256
#define N1      (2*D_INNER)      // 4096

typedef __attribute__((ext_vector_type(8))) __bf16 bf16x8;
typedef __attribute__((ext_vector_type(4))) float f32x4;

__device__ __forceinline__ float b2f(unsigned short u){
  return __uint_as_float(((unsigned int)u) << 16);
}
__device__ __forceinline__ unsigned short f2b(float f){
  unsigned int u = __float_as_uint(f);
  u = (u + 0x7FFFu + ((u >> 16) & 1u)) >> 16;   // RNE
  return (unsigned short)u;
}
__device__ __forceinline__ float softplus_f(float x){
  float r = log1pf(__expf(-fabsf(x)));
  return x > 0.f ? x + r : r;
}

// async 16B global -> LDS (DMA; LDS dst = wave-uniform base + lane*16)
__device__ __forceinline__ void async16(unsigned short* lds, const unsigned short* g){
  __builtin_amdgcn_global_load_lds(
      (const __attribute__((address_space(1))) unsigned int*)g,
      (__attribute__((address_space(3))) unsigned int*)lds, 16, 0, 0);
}

// ---- f32 -> bf16 convert (4 elems/thread) ----
__global__ void cvt_f2b_kernel(const float* __restrict__ src,
                               unsigned short* __restrict__ dst){
  int i = (blockIdx.x * 256 + threadIdx.x) * 4;
  float4 v = *(const float4*)(src + i);
  *(ushort2*)(dst + i)     = (ushort2){f2b(v.x), f2b(v.y)};
  *(ushort2*)(dst + i + 2) = (ushort2){f2b(v.z), f2b(v.w)};
}

// ---- build Acomp(bf16) = [W_dt(2048); W_B(16); W_C(16); zeros(224)] : 2304x2048 ----
__global__ void concat_w_kernel(const float* __restrict__ Wdt,
                                const float* __restrict__ WB,
                                const float* __restrict__ WC,
                                unsigned short* __restrict__ Wcat){
  int idx = blockIdx.x * 256 + threadIdx.x;   // 4-elem granularity
  int row = idx >> 9;                         // 2048 cols = 512 quads/row
  int q   = idx & 511;
  float4 v;
  if      (row < 2048) v = *(const float4*)(Wdt + ((size_t)row * 2048 + q * 4));
  else if (row < 2064) v = *(const float4*)(WB  + ((size_t)(row - 2048) * 2048 + q * 4));
  else if (row < 2080) v = *(const float4*)(WC  + ((size_t)(row - 2064) * 2048 + q * 4));
  else                 v = make_float4(0.f, 0.f, 0.f, 0.f);
  unsigned short* p = Wcat + (size_t)idx * 4;
  *(ushort2*)(p)     = (ushort2){f2b(v.x), f2b(v.y)};
  *(ushort2*)(p + 2) = (ushort2){f2b(v.z), f2b(v.w)};
}

// ---- WxT[k,e] = Win[e,k] (bf16), k<1024, e<2048 (x_ssm half of W_in) ----
__global__ __launch_bounds__(256) void transpose_cvt_kernel(
    const float* __restrict__ Win, unsigned short* __restrict__ WxT){
  __shared__ float t[64][65];
  const int e0 = blockIdx.x * 64;       // source row block (e)
  const int k0 = blockIdx.y * 64;       // source col block (k)
  const int r  = threadIdx.x >> 2;      // 0..63
  const int q  = threadIdx.x & 3;       // 0..3
  #pragma unroll
  for (int jj = 0; jj < 4; jj++){
    float4 v = *(const float4*)&Win[(size_t)(e0 + r) * 1024 + k0 + q*16 + jj*4];
    t[r][q*16 + jj*4 + 0] = v.x; t[r][q*16 + jj*4 + 1] = v.y;
    t[r][q*16 + jj*4 + 2] = v.z; t[r][q*16 + jj*4 + 3] = v.w;
  }
  __syncthreads();
  #pragma unroll
  for (int jj = 0; jj < 2; jj++){
    ushort4 o;
    o.x = f2b(t[q*16 + jj*8 + 0][r]); o.y = f2b(t[q*16 + jj*8 + 1][r]);
    o.z = f2b(t[q*16 + jj*8 + 2][r]); o.w = f2b(t[q*16 + jj*8 + 3][r]);
    *(ushort4*)&WxT[(size_t)(k0 + r) * 2048 + e0 + q*16 + jj*8] = o;
    o.x = f2b(t[q*16 + jj*8 + 4][r]); o.y = f2b(t[q*16 + jj*8 + 5][r]);
    o.z = f2b(t[q*16 + jj*8 + 6][r]); o.w = f2b(t[q*16 + jj*8 + 7][r]);
    *(ushort4*)&WxT[(size_t)(k0 + r) * 2048 + e0 + q*16 + jj*8 + 4] = o;
  }
}

// ---- zero-fill ----
__global__ void zfill_kernel(unsigned short* __restrict__ p){
  p[blockIdx.x * 256 + threadIdx.x] = 0;
}

// ============================================================================
// GEMM: C[M,N] = A[M,K] @ W[N,K]^T, bf16 MFMA, fp32 acc, fused epilogues.
// 256x128 tile, 512 thr = 8 waves (4m x 2n), per-wave output 64x64,
// acc[4][4] = 64 AGPR (r7-verified geometry: VGPR 88, zero spill).
//
// DEEP-PREFETCH SCHEDULE (this rev's change): 3 LDS buffers (A 3x32K,
// B 3x16K = 144 KiB of 160), staging tile t+2 while reading tile t.
// Per K-tile (BK=64): 2 phases, each {ds_read | stage | BAR | lgkmcnt(0) |
// setprio 16xMFMA setprio | BAR}; ONE vmcnt(6) per K-tile at P2-end.
// vmcnt ledger (6 loads/tile: A=4, B=2, issue order uniform):
//   steady iter t: outstanding after P2 issue = tile t+1 (6, issued at
//   iter t-1) + tile t+2 (6, just issued) = 12 -> vmcnt(6) retires tile
//   t+1 (next read) keeping t+2 in flight. Issue->landing-deadline for a
//   tile = ~4 phases >> HBM latency; the old r7 schedule waited on loads
//   issued ONE phase earlier, self-throttling to ~HBM-latency/2-phases
//   (the measured invariant: ~3000 cyc/phase vs 620 cyc of MFMA = 18%
//   MfmaUtil across r0/r5/r7/r8).
//   t = NT-2: nothing staged; outstanding = tile NT-1 (6) -> vmcnt(0).
//   t = NT-1: nothing outstanding, no wait.
// Prologue: stage tile0+tile1 (12 loads), vmcnt(6) -> tile0 landed.
// Hazard: stage target buf (t+2)%3 = tile t-1's buf; its reads retired by
// iter t-1's lgkmcnt(0), and a barrier separates that from iter t's issue.
//
// LDS chunk swizzle (bank-conflict-free, unchanged): 16B slot s of row r
// holds k-chunk s^(r&7); stager pre-swizzles the GLOBAL address (linear
// DMA dst). Reads: slot (kk*4+q)^(m16&7); row&7==m16&7 for all frags.
//
// MODE 0 (fused big GEMM, N=6272 over W = Wcomb):
//   col<2048 -> o0=xs; col<4096 -> o1=z; col<6144 -> o2 dt softplus(+bias),
//   stride SDT; col<6176 -> o2 B/C at +2048; else drop (pad).
// MODE 2: v * sigmoid(bias[0]); store f32 into of (row stride D_MODEL)
// MODE 3: plain bf16 store o0[row*1024+col], guard row<2080 (weight compose)
// ============================================================================
template<int MODE, int K, int GX, int GY>
__global__ __launch_bounds__(512, 1) void gemm_bt(
    const unsigned short* __restrict__ A,
    const unsigned short* __restrict__ W,
    unsigned short* __restrict__ o0,
    unsigned short* __restrict__ o1,
    unsigned short* __restrict__ o2,
    float* __restrict__ of,
    const float* __restrict__ bias)
{
  const int tid  = threadIdx.x;
  const int lane = tid & 63;
  const int w    = tid >> 6;            // 0..7
  const int wm   = w >> 1;              // 0..3 : 64-row quarter of tile
  const int wn   = w & 1;               // 0..1 : 64-col half of tile
  const int m16  = lane & 15, q = lane >> 4;

  // XCD-aware bijective swizzle; NWG % 8 == 0 for all launches
  constexpr int NWG = GX * GY;
  int flat = blockIdx.y * GX + blockIdx.x;
  flat = (flat & 7) * (NWG >> 3) + (flat >> 3);
  const int bm = flat / GX;             // const divisor -> magic mul
  const int bn = flat - bm * GX;

  __shared__ unsigned short sA[3][16384];   // 3 x (256 rows x 64 k) = 96 KB
  __shared__ unsigned short sB[3][8192];    // 3 x (128 rows x 64 k) = 48 KB

  f32x4 acc[4][4];
  #pragma unroll
  for (int i = 0; i < 4; i++)
    #pragma unroll
    for (int j = 0; j < 4; j++) acc[i][j] = (f32x4){0.f, 0.f, 0.f, 0.f};

  // stager: thread -> (row = tid>>3 within 64-row unit, slot = tid&7);
  // fetched global k-chunk = slot ^ (row&7) (pre-swizzled source)
  const int ch = (tid & 7) ^ ((tid >> 3) & 7);
  const unsigned short* Ag = A + (size_t)(bm * 256 + (tid >> 3)) * K + ch * 8;
  const unsigned short* Wg = W + (size_t)(bn * 128 + (tid >> 3)) * K + ch * 8;

  // one stage unit = 1 async16 = 64 rows x 64 k (8 KB across 8 waves)
#define STAGE_A(buf, h, t) do { \
    async16(&sA[buf][(h)*8192 + w*512],        Ag + (size_t)((h)*128    )*K + (t)*64); \
    async16(&sA[buf][(h)*8192 + 4096 + w*512], Ag + (size_t)((h)*128 + 64)*K + (t)*64); \
  } while(0)
#define STAGE_B(buf, t) do { \
    async16(&sB[buf][w*512],        Wg + (size_t)(t)*64); \
    async16(&sB[buf][4096 + w*512], Wg + (size_t)64*K + (t)*64); \
  } while(0)

  // fragment reads: row r, k-chunk kc=(kk*4+q) lives at slot kc^(r&7); r&7==m16&7
#define LDA(dst, buf) do { \
    _Pragma("unroll") for (int mt = 0; mt < 4; mt++) \
    _Pragma("unroll") for (int kk = 0; kk < 2; kk++) { \
      const int row_ = wm*64 + mt*16 + m16; \
      dst[mt][kk] = *(const bf16x8*)&sA[buf][row_*64 + (((kk*4 + q) ^ (m16 & 7)) << 3)]; \
    } } while(0)
#define LDB(dst, buf, nh) do { \
    _Pragma("unroll") for (int nt = 0; nt < 2; nt++) \
    _Pragma("unroll") for (int kk = 0; kk < 2; kk++) { \
      const int row_ = wn*64 + (nh)*32 + nt*16 + m16; \
      dst[nt][kk] = *(const bf16x8*)&sB[buf][row_*64 + (((kk*4 + q) ^ (m16 & 7)) << 3)]; \
    } } while(0)

#define MMAQ(Aa, Bb, NH) do { \
    __builtin_amdgcn_s_setprio(1); \
    _Pragma("unroll") for (int kk = 0; kk < 2; kk++) \
    _Pragma("unroll") for (int mt = 0; mt < 4; mt++) \
    _Pragma("unroll") for (int nt = 0; nt < 2; nt++) \
      acc[mt][(NH)*2 + nt] = __builtin_amdgcn_mfma_f32_16x16x32_bf16( \
          Aa[mt][kk], Bb[nt][kk], acc[mt][(NH)*2 + nt], 0, 0, 0); \
    __builtin_amdgcn_s_setprio(0); \
  } while(0)

#define BAR()  asm volatile("s_barrier" ::: "memory")
#define LGK0() asm volatile("s_waitcnt lgkmcnt(0)" ::: "memory")

  // ---- prologue: tile0 -> buf0, tile1 -> buf1 (12 loads); tile0 landed
  STAGE_A(0, 0, 0); STAGE_A(0, 1, 0); STAGE_B(0, 0);
  STAGE_A(1, 0, 1); STAGE_A(1, 1, 1); STAGE_B(1, 1);
  asm volatile("s_waitcnt vmcnt(6)" ::: "memory");
  BAR();

  constexpr int NT = K >> 6;           // K-tiles of 64
  int cr = 0, cs = 2;                  // read buf, stage buf (tile t+2)
  #pragma unroll 1
  for (int t = 0; t < NT; t++) {
    bf16x8 a[4][2], b[2][2];
    const bool st = (t + 2 < NT);
    // ---- P1: read A(all)+B(h0); stage next-next A ----
    LDA(a, cr); LDB(b, cr, 0);
    if (st) { STAGE_A(cs, 0, t + 2); STAGE_A(cs, 1, t + 2); }
    BAR(); LGK0();
    MMAQ(a, b, 0);
    BAR();
    // ---- P2: read B(h1); stage next-next B; counted vmcnt ----
    LDB(b, cr, 1);
    if (st) STAGE_B(cs, t + 2);
    BAR(); LGK0();
    MMAQ(a, b, 1);
    if (st)                 asm volatile("s_waitcnt vmcnt(6)" ::: "memory");
    else if (t + 1 < NT)    asm volatile("s_waitcnt vmcnt(0)" ::: "memory");
    BAR();
    cr = (cr == 2) ? 0 : cr + 1;
    cs = (cs == 2) ? 0 : cs + 1;
  }

  float gscale = 1.f;
  if (MODE == 2) gscale = 1.f / (1.f + __expf(-bias[0]));

  // C/D layout: col = lane&15, row = (lane>>4)*4 + reg
  const int r0 = bm * 256 + wm * 64 + (q << 2);
  const int c0 = bn * 128 + wn * 64 + m16;
  #pragma unroll
  for (int mt = 0; mt < 4; mt++) {
    #pragma unroll
    for (int nt = 0; nt < 4; nt++) {
      const int col = c0 + nt * 16;
      #pragma unroll
      for (int i = 0; i < 4; i++) {
        const int row = r0 + mt * 16 + i;
        float v = acc[mt][nt][i];
        if (MODE == 0) {
          if      (col < 2048) o0[(size_t)row * D_INNER + col] = f2b(v);
          else if (col < 4096) o1[(size_t)row * D_INNER + (col - 2048)] = f2b(v);
          else if (col < 6144) o2[(size_t)row * SDT + (col - 4096)] =
                                   f2b(softplus_f(v + bias[col - 4096]));
          else if (col < 6176) o2[(size_t)row * SDT + 2048 + (col - 6144)] = f2b(v);
        } else if (MODE == 2) {
          of[(size_t)row * D_MODEL + col] = v * gscale;
        } else {  // MODE 3: weight compose, plain bf16, row stride 1024
          if (row < 2080) o0[(size_t)row * D_MODEL + col] = f2b(v);
        }
      }
    }
  }
#undef STAGE_A
#undef STAGE_B
#undef LDA
#undef LDB
#undef MMAQ
#undef BAR
#undef LGK0
}

// ---- scan pass A: per chunk, per (b,d,n): P = prod A_bar, S = chunk inlet ----
__global__ __launch_bounds__(256) void scan_passA(
    const unsigned short* __restrict__ dtBC,
    const unsigned short* __restrict__ xs,
    const float* __restrict__ Alog,
    float* __restrict__ Pb, float* __restrict__ Sb)
{
  const int d = blockIdx.x * 256 + threadIdx.x;
  const int b = blockIdx.y;
  const int c = blockIdx.z;

  float a[NSTATE];
  #pragma unroll
  for (int n = 0; n < NSTATE; n++) a[n] = -__expf(Alog[d * NSTATE + n]);

  float P[NSTATE], S[NSTATE];
  #pragma unroll
  for (int n = 0; n < NSTATE; n++) { P[n] = 1.f; S[n] = 0.f; }

  __shared__ float sB[16][16];
  const size_t bL = (size_t)b * SEQ;
  const int t0c = c * CLEN;
  const int lt = threadIdx.x >> 4, ln = threadIdx.x & 15;

  for (int t0 = t0c; t0 < t0c + CLEN; t0 += 16) {
    __syncthreads();
    sB[lt][ln] = b2f(dtBC[(bL + t0 + lt) * SDT + 2048 + ln]);
    __syncthreads();
    for (int tt = 0; tt < 16; tt++) {
      const size_t rw = bL + t0 + tt;
      const float dt = b2f(dtBC[rw * SDT + d]);
      const float x  = b2f(xs[rw * D_INNER + d]);
      const float dtx = dt * x;
      #pragma unroll
      for (int n = 0; n < NSTATE; n++) {
        const float ab = __expf(dt * a[n]);   // dt>=0, a<0 => clamp(.,20) dead
        P[n] *= ab;
        S[n] = ab * S[n] + dtx * sB[tt][n];
      }
    }
  }
  const size_t base = (((size_t)c * BATCH + b) * D_INNER + d) * NSTATE;
  #pragma unroll
  for (int n = 0; n < NSTATE; n += 4) {
    *(f32x4*)&Pb[base + n] = (f32x4){P[n], P[n+1], P[n+2], P[n+3]};
    *(f32x4*)&Sb[base + n] = (f32x4){S[n], S[n+1], S[n+2], S[n+3]};
  }
}

// ---- scan pass B: sequential combine across chunks; Pb[c] <- h entering c ----
__global__ __launch_bounds__(256) void scan_passB(float* __restrict__ Pb,
                                                  const float* __restrict__ Sb)
{
  const size_t j = (size_t)blockIdx.x * 256 + threadIdx.x;  // (b,d,n) flat
  const size_t stride = (size_t)BATCH * D_INNER * NSTATE;
  float h = 0.f;
  for (int c = 0; c < NCHUNK; c++) {
    const size_t idx = (size_t)c * stride + j;
    const float p = Pb[idx];
    const float s = Sb[idx];
    Pb[idx] = h;
    h = p * h + s;
  }
}

// ---- scan pass C: re-scan chunk with true h0; y=(scan + x*D)*silu(z) ----
// NOTE: yb may alias zb (each thread reads z[rw,d] before writing y[rw,d]).
__global__ __launch_bounds__(256) void scan_passC(
    const unsigned short* __restrict__ dtBC,
    const unsigned short* __restrict__ xs,
    const unsigned short* __restrict__ zb,
    const float* __restrict__ Alog,
    const float* __restrict__ Dv,
    const float* __restrict__ Hb,
    unsigned short* __restrict__ yb)
{
  const int d = blockIdx.x * 256 + threadIdx.x;
  const int b = blockIdx.y;
  const int c = blockIdx.z;

  float a[NSTATE];
  #pragma unroll
  for (int n = 0; n < NSTATE; n++) a[n] = -__expf(Alog[d * NSTATE + n]);

  float h[NSTATE];
  const size_t base = (((size_t)c * BATCH + b) * D_INNER + d) * NSTATE;
  #pragma unroll
  for (int n = 0; n < NSTATE; n += 4) {
    f32x4 v = *(const f32x4*)&Hb[base + n];
    h[n] = v.x; h[n+1] = v.y; h[n+2] = v.z; h[n+3] = v.w;
  }
  const float Dd = Dv[d];

  __shared__ float sB[16][16];
  __shared__ float sC[16][16];
  const size_t bL = (size_t)b * SEQ;
  const int t0c = c * CLEN;
  const int lt = threadIdx.x >> 4, ln = threadIdx.x & 15;

  for (int t0 = t0c; t0 < t0c + CLEN; t0 += 16) {
    __syncthreads();
    {
      const size_t rwb = (bL + t0 + lt) * SDT + 2048;
      sB[lt][ln] = b2f(dtBC[rwb + ln]);
      sC[lt][ln] = b2f(dtBC[rwb + 16 + ln]);
    }
    __syncthreads();
    for (int tt = 0; tt < 16; tt++) {
      const size_t rw = bL + t0 + tt;
      const float dt = b2f(dtBC[rw * SDT + d]);
      const float x  = b2f(xs[rw * D_INNER + d]);
      const float z  = b2f(zb[rw * D_INNER + d]);
      const float dtx = dt * x;
      float y = 0.f;
      #pragma unroll
      for (int n = 0; n < NSTATE; n++) {
        const float ab = __expf(dt * a[n]);
        h[n] = ab * h[n] + dtx * sB[tt][n];
        y += h[n] * sC[tt][n];
      }
      y = (y + x * Dd) * (z / (1.f + __expf(-z)));   // +x*D, *silu(z)
      yb[rw * D_INNER + d] = f2b(y);
    }
  }
}

extern "C" void kernel_launch(void* const* d_in, const int* in_sizes, int n_in,
                              void* d_out, int out_size, void* d_ws, size_t ws_size,
                              hipStream_t stream)
{
  const float* x    = (const float*)d_in[0];   // (4,4096,1024)
  const float* Win  = (const float*)d_in[1];   // (4096,1024)
  const float* Alog = (const float*)d_in[2];   // (2048,16)
  const float* WB   = (const float*)d_in[3];   // (16,2048)
  const float* WC   = (const float*)d_in[4];   // (16,2048)
  const float* Wdt  = (const float*)d_in[5];   // (2048,2048)
  const float* bdt  = (const float*)d_in[6];   // (2048,)
  const float* Dv   = (const float*)d_in[7];   // (2048,)
  const float* gate = (const float*)d_in[8];   // (1,)
  const float* Wout = (const float*)d_in[9];   // (1024,2048)
  float* outp = (float*)d_out;                 // (4,4096,1024) f32

  // ---- d_ws layout (208 MiB, unchanged footprint) ----
  char* ws = (char*)d_ws;
  unsigned short* xs    = (unsigned short*)(ws + 0);          // 16384x2048 bf16 (67.1 MB)
  unsigned short* zy    = (unsigned short*)(ws + 67108864);   // z, later y (aliased)
  unsigned short* dtBC  = (unsigned short*)(ws + 134217728);  // 16384x2176 bf16 (71.3 MB)
  unsigned short* WxT   = (unsigned short*)(ws + 205520896);  // 1024x2048 bf16 (4 MB)
  unsigned short* Woutb = (unsigned short*)(ws + 213909504);  // 1024x2048 bf16 (4 MB)

  // ---- d_out (67.1 MB f32) doubles as scratch before final GEMM writes it ----
  char* ob = (char*)d_out;
  float* Pb = (float*)(ob + 0);                               // 16x4x2048x16 f32 (8 MB)
  float* Sb = (float*)(ob + 8388608);                         // (8 MB)
  unsigned short* Acomp = (unsigned short*)(ob + 0);          // 2304x2048 bf16 — pre-scan only
  unsigned short* Wcomb = (unsigned short*)(ob + 16777216);   // 6272x1024 bf16 (12.8 MB)
  unsigned short* xb    = (unsigned short*)(ob + 33554432);   // 16384x1024 bf16 (33.5 MB)

  // prep: conversions + composed-weight build
  cvt_f2b_kernel<<<16384, 256, 0, stream>>>(x, xb);
  cvt_f2b_kernel<<<4096, 256, 0, stream>>>(Win, Wcomb);            // Wcomb rows 0..4095 = Win
  cvt_f2b_kernel<<<2048, 256, 0, stream>>>(Wout, Woutb);
  concat_w_kernel<<<(NCATP * D_INNER / 4) / 256, 256, 0, stream>>>(Wdt, WB, WC, Acomp);
  transpose_cvt_kernel<<<dim3(32, 16), 256, 0, stream>>>(Win, WxT);
  zfill_kernel<<<384, 256, 0, stream>>>(Wcomb + (size_t)6176 * 1024);  // pad rows 6176..6271

  // compose: Wcomb[4096+j, k] = sum_e Acomp[j,e] * Win[e,k]  (j<2080 real)
  gemm_bt<3, 2048, 8, 9><<<dim3(8, 9), 512, 0, stream>>>(
      Acomp, WxT, Wcomb + (size_t)4096 * 1024, nullptr, nullptr, nullptr, nullptr);

  // fused big GEMM: [xs | z | dt(softplus) | B C] = x @ Wcomb^T
  gemm_bt<0, D_MODEL, NBIG / 128, MTOT / 256><<<dim3(NBIG / 128, MTOT / 256), 512, 0, stream>>>(
      xb, Wcomb, xs, zy, dtBC, nullptr, bdt);

  scan_passA<<<dim3(D_INNER / 256, BATCH, NCHUNK), 256, 0, stream>>>(
      dtBC, xs, Alog, Pb, Sb);
  scan_passB<<<(BATCH * D_INNER * NSTATE) / 256, 256, 0, stream>>>(Pb, Sb);
  scan_passC<<<dim3(D_INNER / 256, BATCH, NCHUNK), 256, 0, stream>>>(
      dtBC, xs, zy, Alog, Dv, Pb, zy);
  gemm_bt<2, D_INNER, D_MODEL / 128, MTOT / 256><<<dim3(D_MODEL / 128, MTOT / 256), 512, 0, stream>>>(
      zy, Woutb, nullptr, nullptr, nullptr, outp, gate);
}